// Round 12
// baseline (1481.117 us; speedup 1.0000x reference)
//
#include <hip/hip_runtime.h>

// TdLstm: twin BasicLSTM (i,j,f,o; forget_bias=1) + final dense.
// Round 12: r10 structure (128 WGs x 512 threads, u-width 64, groups of 8)
// with the r10 bug fixed: __launch_bounds__(512,1) -> 2 waves/SIMD -> 256
// VGPR/wave budget (r10's (512,2) capped at 128 and spilled all of W).
// Per-wave MFMA/register shape = proven r6 (2 M-frags x 26 kt = 208 VGPRs).
// Proven L3 agent-counter protocol.
// ws: [0,2048) barrier counters (memset), [4096,+1MiB) h ping-pong (bf16),
// then 1MiB final h (f32).

using bf16x8 = __attribute__((ext_vector_type(8))) __bf16;
using f32x4  = __attribute__((ext_vector_type(4))) float;
using u32x4  = __attribute__((ext_vector_type(4))) unsigned int;
typedef unsigned short u16;
typedef unsigned long long u64;

#define NT 128
#define ROWB 1664                                  // 832 k-elems * 2B per B-row
#define SWZ(row, off) ((off) ^ (((row) & 7) << 4)) // bank swizzle, 16B granules

#define LGKM0  asm volatile("s_waitcnt lgkmcnt(0)" ::: "memory")
#define VM0    asm volatile("s_waitcnt vmcnt(0)" ::: "memory")
#define BAR()  __builtin_amdgcn_s_barrier()
#define SCHED0 __builtin_amdgcn_sched_barrier(0)

__device__ __forceinline__ u16 f2bf(float f) {
  union { float f; unsigned u; } v; v.f = f;
  unsigned r = v.u + 0x7fffu + ((v.u >> 16) & 1u);
  return (u16)(r >> 16);
}
__device__ __forceinline__ float sigf(float x) { return 1.f / (1.f + __expf(-x)); }
__device__ __forceinline__ float tanhf_(float x) { return 2.f / (1.f + __expf(-2.f * x)) - 1.f; }

// static-index store into A-fragment array (avoid scratch, rule #20)
__device__ __forceinline__ void setA26(bf16x8 (&A)[26], int kt, bf16x8 v) {
  switch (kt) {
    case 0:A[0]=v;break;  case 1:A[1]=v;break;  case 2:A[2]=v;break;
    case 3:A[3]=v;break;  case 4:A[4]=v;break;  case 5:A[5]=v;break;
    case 6:A[6]=v;break;  case 7:A[7]=v;break;  case 8:A[8]=v;break;
    case 9:A[9]=v;break;  case 10:A[10]=v;break; case 11:A[11]=v;break;
    case 12:A[12]=v;break; case 13:A[13]=v;break; case 14:A[14]=v;break;
    case 15:A[15]=v;break; case 16:A[16]=v;break; case 17:A[17]=v;break;
    case 18:A[18]=v;break; case 19:A[19]=v;break; case 20:A[20]=v;break;
    case 21:A[21]=v;break; case 22:A[22]=v;break; case 23:A[23]=v;break;
    case 24:A[24]=v;break; case 25:A[25]=v;break;
  }
}

__global__ __launch_bounds__(512, 1) void lstm_persist(
    const int* __restrict__ lids, const int* __restrict__ rids,
    const int* __restrict__ llen, const int* __restrict__ rlen,
    const float* __restrict__ emb,
    const float* __restrict__ Wl, const float* __restrict__ bl,
    const float* __restrict__ Wr, const float* __restrict__ br,
    u64* __restrict__ hbuf,      // [2 lstm][2 buf][256][128] u64 (bf16 x4)
    float* __restrict__ hfin,    // [2 lstm][256][512] f32
    unsigned int* __restrict__ bar)
{
  __shared__ __align__(16) unsigned char sB[32 * ROWB]; // 52 KiB (also W scratch)
  __shared__ __align__(8)  u16 sH[32][72];              // h-out staging (4.5 KiB)
  __shared__ int sI[4096];                              // ids[32 rows][128 t]

  const int tid = threadIdx.x;
  const int w = tid >> 6, l = tid & 63;       // 8 waves
  const int bid = blockIdx.x;                 // 0..127
  const int xcd = bid & 7, idx = bid >> 3;    // idx 0..15
  const int grp = xcd * 2 + (idx >> 3);       // 0..15 (lstm x b-tile)
  const int ct  = idx & 7;                    // u-tile: u0 = ct*64
  const int lstm = grp >> 3, bt = grp & 7;
  const int b0 = bt * 32, u0 = ct * 64;

  const int*   ids  = lstm ? rids : lids;
  const int*   lenp = lstm ? rlen : llen;
  const float* W    = lstm ? Wr : Wl;
  const float* bv   = lstm ? br : bl;
  unsigned int* const blp = bar + grp * 32;   // L3 agent counter

  // ---- one-time: W^T A-frags. wave w owns mf=2w,2w+1 (16 frags = 256 rows)
  // staged in 13 k-chunks x 2 column-halves of the 64-wide u-tile.
  bf16x8 A0[26], A1[26];
  {
    float* sW = (float*)sB;                   // [4 g][64 r][32 c] = 32 KiB
    for (int kc = 0; kc < 13; ++kc)
      for (int ch = 0; ch < 2; ++ch) {
        for (int i = 0; i < 16; ++i) {
          int id2 = tid + i * 512;
          int c = id2 & 31, r = (id2 >> 5) & 63, g = id2 >> 11;
          int kk = kc * 64 + r;
          float v = 0.f;
          if (kk < 300)       v = W[kk * 2048 + g * 512 + u0 + ch * 32 + c];
          else if (kk >= 320) v = W[(kk - 20) * 2048 + g * 512 + u0 + ch * 32 + c];
          sW[(g * 64 + r) * 32 + c] = v;
        }
        __syncthreads();
        #pragma unroll
        for (int kt2 = 0; kt2 < 2; ++kt2) {
          int kt = kc * 2 + kt2;
          #pragma unroll
          for (int mf2 = 0; mf2 < 2; ++mf2) {
            int mf = 2 * w + mf2;
            int rho = mf * 16 + (l & 15);     // A-row; col map rho = du*4 + g
            int du = rho >> 2, g = rho & 3;
            if ((du >> 5) == ch) {
              int cc = du & 31;
              union { u16 s[8]; bf16x8 v; } tmp;
              #pragma unroll
              for (int j = 0; j < 8; ++j) {
                int kr = kt2 * 32 + ((l >> 4) << 3) + j;
                tmp.s[j] = f2bf(sW[(g * 64 + kr) * 32 + cc]);
              }
              if (mf2 == 0) setA26(A0, kt, tmp.v); else setA26(A1, kt, tmp.v);
            }
          }
        }
        __syncthreads();
      }
  }

  // zero-pad x region k in [300,320)
  if (tid < 160) {
    int row = tid / 5, c5 = tid - (tid / 5) * 5;
    *(u64*)(sB + row * ROWB + SWZ(row, 600 + c5 * 8)) = 0ULL;
  }
  // preload ids for this b-tile: 4096 ints
  {
    const int* src = ids + b0 * NT;
    #pragma unroll
    for (int i = 0; i < 2; ++i)
      *(int4*)&sI[(tid + i * 512) * 4] = *(const int4*)&src[(tid + i * 512) * 4];
  }

  int ldsoff[5], sirow[5], foff[5];
  #pragma unroll
  for (int i = 0; i < 5; ++i) {
    int id2 = tid + i * 512;
    int row = (id2 < 2400) ? id2 / 75 : 0;
    int f4  = id2 - row * 75;
    ldsoff[i] = row * ROWB + SWZ(row, f4 * 8);
    sirow[i]  = row * NT;
    foff[i]   = f4 * 4;
  }
  int hoff[8];
  #pragma unroll
  for (int i = 0; i < 8; ++i) {
    int id2 = tid + i * 512;
    int row = id2 >> 7, c8 = id2 & 127;
    hoff[i] = row * ROWB + SWZ(row, 640 + c8 * 8);
  }

  int lenn[2];
  lenn[0] = lenp[b0 + (l & 15)];
  lenn[1] = lenp[b0 + 16 + (l & 15)];
  float bia[2][4];
  #pragma unroll
  for (int mf2 = 0; mf2 < 2; ++mf2) {
    int du = w * 8 + mf2 * 4 + (l >> 4);      // [0,64)
    #pragma unroll
    for (int g = 0; g < 4; ++g) bia[mf2][g] = bv[g * 512 + u0 + du];
  }
  float cst[2][2] = {{0.f, 0.f}, {0.f, 0.f}};
  float hst[2][2] = {{0.f, 0.f}, {0.f, 0.f}};
  __syncthreads();

  // prologue: stage x(0), prefetch x(1)
  float4 px[5];
  #pragma unroll
  for (int i = 0; i < 5; ++i)
    if (i < 4 || tid < 352) {
      int eid = sI[sirow[i]];
      float4 xv = *(const float4*)(emb + eid * 300 + foff[i]);
      u64 pk = (u64)f2bf(xv.x) | ((u64)f2bf(xv.y) << 16) |
               ((u64)f2bf(xv.z) << 32) | ((u64)f2bf(xv.w) << 48);
      *(u64*)(sB + ldsoff[i]) = pk;
    }
  #pragma unroll
  for (int i = 0; i < 5; ++i)
    if (i < 4 || tid < 352) {
      int eid = sI[sirow[i] + 1];
      px[i] = *(const float4*)(emb + eid * 300 + foff[i]);
    }
  __syncthreads();

  const int r0 = l & 15, r1 = 16 + (l & 15);

  // x-GEMM(0): kt 0..9 (k < 320: x + zero pad)
  f32x4 xacc[2][2];
  xacc[0][0] = {0.f,0.f,0.f,0.f}; xacc[0][1] = {0.f,0.f,0.f,0.f};
  xacc[1][0] = {0.f,0.f,0.f,0.f}; xacc[1][1] = {0.f,0.f,0.f,0.f};
  #pragma unroll
  for (int kt = 0; kt < 10; ++kt) {
    int kb = kt * 64 + ((l >> 4) << 4);
    bf16x8 B0 = __builtin_bit_cast(bf16x8, *(const u32x4*)(sB + r0 * ROWB + SWZ(r0, kb)));
    bf16x8 B1 = __builtin_bit_cast(bf16x8, *(const u32x4*)(sB + r1 * ROWB + SWZ(r1, kb)));
    xacc[0][0] = __builtin_amdgcn_mfma_f32_16x16x32_bf16(A0[kt], B0, xacc[0][0], 0, 0, 0);
    xacc[0][1] = __builtin_amdgcn_mfma_f32_16x16x32_bf16(A0[kt], B1, xacc[0][1], 0, 0, 0);
    xacc[1][0] = __builtin_amdgcn_mfma_f32_16x16x32_bf16(A1[kt], B0, xacc[1][0], 0, 0, 0);
    xacc[1][1] = __builtin_amdgcn_mfma_f32_16x16x32_bf16(A1[kt], B1, xacc[1][1], 0, 0, 0);
  }

  for (int t = 0; t < NT; ++t) {
    if (t > 0) {
      // detect: 8 producers per group at L3 (proven protocol)
      if (tid == 0) {
        unsigned target = 8u * (unsigned)t;
        while (__hip_atomic_load(blp, __ATOMIC_RELAXED, __HIP_MEMORY_SCOPE_AGENT) < target)
          __builtin_amdgcn_s_sleep(1);
      }
      BAR(); SCHED0;
      // h(t-1) loads (L3-coherent) -> LDS: 4096 u64 over 512 threads
      const u64* hsrc = hbuf + (((lstm * 2 + ((t & 1) ^ 1)) * 256) + b0) * 128;
      u64 hld[8];
      #pragma unroll
      for (int i = 0; i < 8; ++i)
        hld[i] = __hip_atomic_load(&hsrc[tid + i * 512], __ATOMIC_RELAXED,
                                   __HIP_MEMORY_SCOPE_AGENT);
      #pragma unroll
      for (int i = 0; i < 8; ++i) *(u64*)(sB + hoff[i]) = hld[i];
      LGKM0; BAR(); SCHED0;
      // h-GEMM: kt 10..25 (k in [320,832)), accumulate into xacc
      #pragma unroll
      for (int kt = 10; kt < 26; ++kt) {
        int kb = kt * 64 + ((l >> 4) << 4);
        bf16x8 B0 = __builtin_bit_cast(bf16x8, *(const u32x4*)(sB + r0 * ROWB + SWZ(r0, kb)));
        bf16x8 B1 = __builtin_bit_cast(bf16x8, *(const u32x4*)(sB + r1 * ROWB + SWZ(r1, kb)));
        xacc[0][0] = __builtin_amdgcn_mfma_f32_16x16x32_bf16(A0[kt], B0, xacc[0][0], 0, 0, 0);
        xacc[0][1] = __builtin_amdgcn_mfma_f32_16x16x32_bf16(A0[kt], B1, xacc[0][1], 0, 0, 0);
        xacc[1][0] = __builtin_amdgcn_mfma_f32_16x16x32_bf16(A1[kt], B0, xacc[1][0], 0, 0, 0);
        xacc[1][1] = __builtin_amdgcn_mfma_f32_16x16x32_bf16(A1[kt], B1, xacc[1][1], 0, 0, 0);
      }
    }

    // gates (acc reg r == gate r for cell (b,u): i,j,f,o)
    #pragma unroll
    for (int mf2 = 0; mf2 < 2; ++mf2)
      #pragma unroll
      for (int n = 0; n < 2; ++n) {
        f32x4 z = xacc[mf2][n];
        float zi = z[0] + bia[mf2][0];
        float zj = z[1] + bia[mf2][1];
        float zf = z[2] + bia[mf2][2];
        float zo = z[3] + bia[mf2][3];
        float cn = cst[mf2][n] * sigf(zf + 1.f) + sigf(zi) * tanhf_(zj);
        float hn = tanhf_(cn) * sigf(zo);
        if (t < lenn[n]) { cst[mf2][n] = cn; hst[mf2][n] = hn; }
        sH[n * 16 + (l & 15)][w * 8 + mf2 * 4 + (l >> 4)] = f2bf(hst[mf2][n]);
      }
    LGKM0; BAR(); SCHED0;

    // pack + coalesced u64 store of h(t) (32 rows x 64 u per WG)
    {
      int bbL = tid >> 4, u8 = tid & 15;
      u64 pk = *(const u64*)&sH[bbL][u8 * 4];
      u64* hdst = hbuf + (((lstm * 2 + (t & 1)) * 256) + b0 + bbL) * 128 + ct * 16 + u8;
      __hip_atomic_store(hdst, pk, __ATOMIC_RELAXED, __HIP_MEMORY_SCOPE_AGENT);
    }
    // stage x(t+1) from px regs into LDS (hides under store-ack)
    #pragma unroll
    for (int i = 0; i < 5; ++i)
      if (i < 4 || tid < 352) {
        float4 xv = px[i];
        u64 pk = (u64)f2bf(xv.x) | ((u64)f2bf(xv.y) << 16) |
                 ((u64)f2bf(xv.z) << 32) | ((u64)f2bf(xv.w) << 48);
        *(u64*)(sB + ldsoff[i]) = pk;
      }
    VM0; LGKM0; BAR();   // h committed before signaling

    // arrive
    if (tid == 0)
      __hip_atomic_fetch_add(blp, 1u, __ATOMIC_RELAXED, __HIP_MEMORY_SCOPE_AGENT);
    SCHED0;

    // prefetch x(t+2)
    {
      int tn2 = (t + 2) & (NT - 1);
      #pragma unroll
      for (int i = 0; i < 5; ++i)
        if (i < 4 || tid < 352) {
          int eid = sI[sirow[i] + tn2];
          px[i] = *(const float4*)(emb + eid * 300 + foff[i]);
        }
    }
    // x-GEMM(t+1): kt 0..9 into fresh xacc (in barrier-skew shadow)
    xacc[0][0] = {0.f,0.f,0.f,0.f}; xacc[0][1] = {0.f,0.f,0.f,0.f};
    xacc[1][0] = {0.f,0.f,0.f,0.f}; xacc[1][1] = {0.f,0.f,0.f,0.f};
    #pragma unroll
    for (int kt = 0; kt < 10; ++kt) {
      int kb = kt * 64 + ((l >> 4) << 4);
      bf16x8 B0 = __builtin_bit_cast(bf16x8, *(const u32x4*)(sB + r0 * ROWB + SWZ(r0, kb)));
      bf16x8 B1 = __builtin_bit_cast(bf16x8, *(const u32x4*)(sB + r1 * ROWB + SWZ(r1, kb)));
      xacc[0][0] = __builtin_amdgcn_mfma_f32_16x16x32_bf16(A0[kt], B0, xacc[0][0], 0, 0, 0);
      xacc[0][1] = __builtin_amdgcn_mfma_f32_16x16x32_bf16(A0[kt], B1, xacc[0][1], 0, 0, 0);
      xacc[1][0] = __builtin_amdgcn_mfma_f32_16x16x32_bf16(A1[kt], B0, xacc[1][0], 0, 0, 0);
      xacc[1][1] = __builtin_amdgcn_mfma_f32_16x16x32_bf16(A1[kt], B1, xacc[1][1], 0, 0, 0);
    }
  }

  #pragma unroll
  for (int mf2 = 0; mf2 < 2; ++mf2)
    #pragma unroll
    for (int n = 0; n < 2; ++n) {
      int bb = b0 + n * 16 + (l & 15);
      int uu = u0 + w * 8 + mf2 * 4 + (l >> 4);
      hfin[lstm * (256 * 512) + bb * 512 + uu] = hst[mf2][n];
    }
}

__global__ void dense_out(const float* __restrict__ hfin,
                          const float* __restrict__ Wd, const float* __restrict__ bd,
                          float* __restrict__ out) {
  const int b = blockIdx.x, l = threadIdx.x;
  float a0 = 0.f, a1 = 0.f, a2 = 0.f;
  for (int i = l; i < 1024; i += 64) {
    float hv = (i < 512) ? hfin[b * 512 + i] : hfin[256 * 512 + b * 512 + (i - 512)];
    a0 += hv * Wd[i * 3 + 0];
    a1 += hv * Wd[i * 3 + 1];
    a2 += hv * Wd[i * 3 + 2];
  }
  #pragma unroll
  for (int off = 32; off > 0; off >>= 1) {
    a0 += __shfl_down(a0, off);
    a1 += __shfl_down(a1, off);
    a2 += __shfl_down(a2, off);
  }
  if (l == 0) {
    out[b * 3 + 0] = a0 + bd[0];
    out[b * 3 + 1] = a1 + bd[1];
    out[b * 3 + 2] = a2 + bd[2];
  }
}

extern "C" void kernel_launch(void* const* d_in, const int* in_sizes, int n_in,
                              void* d_out, int out_size, void* d_ws, size_t ws_size,
                              hipStream_t stream) {
  const int*   lids = (const int*)d_in[0];
  const int*   rids = (const int*)d_in[1];
  const int*   llen = (const int*)d_in[2];
  const int*   rlen = (const int*)d_in[3];
  const float* emb  = (const float*)d_in[4];
  const float* Wl   = (const float*)d_in[5];
  const float* bl   = (const float*)d_in[6];
  const float* Wr   = (const float*)d_in[7];
  const float* br   = (const float*)d_in[8];
  const float* Wd   = (const float*)d_in[9];
  const float* bd   = (const float*)d_in[10];

  unsigned char* ws = (unsigned char*)d_ws;
  unsigned int* bar = (unsigned int*)ws;             // 16 groups * 128B
  u64*   hbuf = (u64*)(ws + 4096);                   // 1 MiB
  float* hfin = (float*)(ws + 4096 + (1u << 20));    // 1 MiB

  hipMemsetAsync(bar, 0, 2048, stream);              // re-arm barrier each call
  hipLaunchKernelGGL(lstm_persist, dim3(128), dim3(512), 0, stream,
                     lids, rids, llen, rlen, emb, Wl, bl, Wr, br, hbuf, hfin, bar);
  hipLaunchKernelGGL(dense_out, dim3(256), dim3(64), 0, stream,
                     hfin, Wd, bd, (float*)d_out);
}

// Round 13
// 732.353 us; speedup vs baseline: 2.0224x; 2.0224x over previous
//
#include <hip/hip_runtime.h>

// TdLstm: twin BasicLSTM (i,j,f,o; forget_bias=1) + final dense.
// Round 13: SELF-TIMED dataflow. No barriers/counters between WGs: each h
// value stored as u32 = (bf16<<16)|step_tag via agent stores; consumers
// poll the tagged words directly (agent u64 loads, r6-proven) and retry
// until all tags match t-1. Arrive/detect/store-ack chain deleted.
// Dense layer folded to per-WG partials + tiny reduce kernel.
// ws: [4096, +2MiB) tagged h ping-pong (memset 0xFF each call),
// then 96KiB dense partials [2 lstm][16 ct][256 b][3].

using bf16x8 = __attribute__((ext_vector_type(8))) __bf16;
using f32x4  = __attribute__((ext_vector_type(4))) float;
using u32x4  = __attribute__((ext_vector_type(4))) unsigned int;
typedef unsigned short u16;
typedef unsigned int u32;
typedef unsigned long long u64;

#define NT 128
#define ROWB 1664                                  // 832 k-elems * 2B per B-row
#define SWZ(row, off) ((off) ^ (((row) & 7) << 4)) // bank swizzle, 16B granules

#define LGKM0  asm volatile("s_waitcnt lgkmcnt(0)" ::: "memory")
#define BAR()  __builtin_amdgcn_s_barrier()
#define SCHED0 __builtin_amdgcn_sched_barrier(0)

__device__ __forceinline__ u16 f2bf(float f) {
  union { float f; unsigned u; } v; v.f = f;
  unsigned r = v.u + 0x7fffu + ((v.u >> 16) & 1u);
  return (u16)(r >> 16);
}
__device__ __forceinline__ float sigf(float x) { return 1.f / (1.f + __expf(-x)); }
__device__ __forceinline__ float tanhf_(float x) { return 2.f / (1.f + __expf(-2.f * x)) - 1.f; }

// static-index store into A-fragment array (avoid scratch, rule #20)
__device__ __forceinline__ void setA26(bf16x8 (&A)[26], int kt, bf16x8 v) {
  switch (kt) {
    case 0:A[0]=v;break;  case 1:A[1]=v;break;  case 2:A[2]=v;break;
    case 3:A[3]=v;break;  case 4:A[4]=v;break;  case 5:A[5]=v;break;
    case 6:A[6]=v;break;  case 7:A[7]=v;break;  case 8:A[8]=v;break;
    case 9:A[9]=v;break;  case 10:A[10]=v;break; case 11:A[11]=v;break;
    case 12:A[12]=v;break; case 13:A[13]=v;break; case 14:A[14]=v;break;
    case 15:A[15]=v;break; case 16:A[16]=v;break; case 17:A[17]=v;break;
    case 18:A[18]=v;break; case 19:A[19]=v;break; case 20:A[20]=v;break;
    case 21:A[21]=v;break; case 22:A[22]=v;break; case 23:A[23]=v;break;
    case 24:A[24]=v;break; case 25:A[25]=v;break;
  }
}

__global__ __launch_bounds__(256, 1) void lstm_persist(
    const int* __restrict__ lids, const int* __restrict__ rids,
    const int* __restrict__ llen, const int* __restrict__ rlen,
    const float* __restrict__ emb,
    const float* __restrict__ Wl, const float* __restrict__ bl,
    const float* __restrict__ Wr, const float* __restrict__ br,
    const float* __restrict__ Wd,
    u64* __restrict__ hbuf,      // [2 lstm][2 buf][256 b][256 u64] tagged u32 h
    float* __restrict__ part)    // [2 lstm][16 ct][256 b][3] dense partials
{
  __shared__ __align__(16) unsigned char sB[32 * ROWB]; // 52 KiB (also W scratch)
  __shared__ __align__(8)  u16 sH[32][36];              // h-out staging
  __shared__ int sI[4096];                              // ids[32 rows][128 t]
  __shared__ float sOut[32][3];                         // dense partial reduce

  const int tid = threadIdx.x;
  const int w = tid >> 6, l = tid & 63;
  const int bid = blockIdx.x;
  const int xcd = bid & 7, idx = bid >> 3;
  const int grp = xcd * 2 + (idx >> 4);   // 0..15 (lstm x b-tile)
  const int ct  = idx & 15;               // u-tile: u0 = ct*32
  const int lstm = grp >> 3, bt = grp & 7;
  const int b0 = bt * 32, u0 = ct * 32;

  const int*   ids  = lstm ? rids : lids;
  const int*   lenp = lstm ? rlen : llen;
  const float* W    = lstm ? Wr : Wl;
  const float* bv   = lstm ? br : bl;

  // ---- one-time: build W^T A-fragments (M-split: wave w owns mf=2w,2w+1) ----
  bf16x8 A0[26], A1[26];
  {
    float* sW = (float*)sB;                // [4 g][64 r][32 c] = 32 KiB scratch
    for (int kc = 0; kc < 13; ++kc) {
      for (int i = 0; i < 32; ++i) {
        int id2 = tid + i * 256;
        int c = id2 & 31, r = (id2 >> 5) & 63, g = id2 >> 11;
        int kk = kc * 64 + r;
        float v = 0.f;
        if (kk < 300)       v = W[kk * 2048 + g * 512 + u0 + c];
        else if (kk >= 320) v = W[(kk - 20) * 2048 + g * 512 + u0 + c];
        sW[(g * 64 + r) * 32 + c] = v;
      }
      __syncthreads();
      #pragma unroll
      for (int kt2 = 0; kt2 < 2; ++kt2) {
        int kt = kc * 2 + kt2;
        #pragma unroll
        for (int mf2 = 0; mf2 < 2; ++mf2) {
          int mf = w * 2 + mf2;
          int rho = mf * 16 + (l & 15);    // col map rho = du*4 + g
          int du = rho >> 2, g = rho & 3;
          union { u16 s[8]; bf16x8 v; } tmp;
          #pragma unroll
          for (int j = 0; j < 8; ++j) {
            int kr = kt2 * 32 + ((l >> 4) << 3) + j;
            tmp.s[j] = f2bf(sW[(g * 64 + kr) * 32 + du]);
          }
          if (mf2 == 0) setA26(A0, kt, tmp.v); else setA26(A1, kt, tmp.v);
        }
      }
      __syncthreads();
    }
  }

  // zero-pad x region k in [300,320)
  if (tid < 160) {
    int row = tid / 5, c5 = tid - (tid / 5) * 5;
    *(u64*)(sB + row * ROWB + SWZ(row, 600 + c5 * 8)) = 0ULL;
  }
  // preload ids for this b-tile
  {
    const int* src = ids + b0 * NT;
    #pragma unroll
    for (int i = 0; i < 4; ++i)
      *(int4*)&sI[(tid + i * 256) * 4] = *(const int4*)&src[(tid + i * 256) * 4];
  }

  int ldsoff[10], sirow[10], foff[10];
  #pragma unroll
  for (int i = 0; i < 10; ++i) {
    int id2 = tid + i * 256;
    int row = (id2 < 2400) ? id2 / 75 : 0;
    int f4 = id2 - row * 75;
    ldsoff[i] = row * ROWB + SWZ(row, f4 * 8);
    sirow[i]  = row * NT;
    foff[i]   = f4 * 4;
  }

  int lenn[2];
  lenn[0] = lenp[b0 + (l & 15)];
  lenn[1] = lenp[b0 + 16 + (l & 15)];
  float bia[2][4];
  #pragma unroll
  for (int mf2 = 0; mf2 < 2; ++mf2) {
    int du = w * 8 + mf2 * 4 + (l >> 4);
    #pragma unroll
    for (int g = 0; g < 4; ++g) bia[mf2][g] = bv[g * 512 + u0 + du];
  }
  float cst[2][2] = {{0.f, 0.f}, {0.f, 0.f}};
  float hst[2][2] = {{0.f, 0.f}, {0.f, 0.f}};
  __syncthreads();

  // prologue: stage x(0), prefetch x(1)
  float4 px[10];
  #pragma unroll
  for (int i = 0; i < 10; ++i)
    if (i < 9 || tid < 96) {
      int eid = sI[sirow[i]];
      float4 xv = *(const float4*)(emb + eid * 300 + foff[i]);
      u64 pk = (u64)f2bf(xv.x) | ((u64)f2bf(xv.y) << 16) |
               ((u64)f2bf(xv.z) << 32) | ((u64)f2bf(xv.w) << 48);
      *(u64*)(sB + ldsoff[i]) = pk;
    }
  #pragma unroll
  for (int i = 0; i < 10; ++i)
    if (i < 9 || tid < 96) {
      int eid = sI[sirow[i] + 1];
      px[i] = *(const float4*)(emb + eid * 300 + foff[i]);
    }
  __syncthreads();

  const int r0 = l & 15, r1 = 16 + (l & 15);

  // x-GEMM(0): kt 0..9 (k < 320 region, x + zero pad)
  f32x4 xacc[2][2];
  xacc[0][0] = {0.f,0.f,0.f,0.f}; xacc[0][1] = {0.f,0.f,0.f,0.f};
  xacc[1][0] = {0.f,0.f,0.f,0.f}; xacc[1][1] = {0.f,0.f,0.f,0.f};
  #pragma unroll
  for (int kt = 0; kt < 10; ++kt) {
    int kb = kt * 64 + ((l >> 4) << 4);
    bf16x8 B0 = __builtin_bit_cast(bf16x8, *(const u32x4*)(sB + r0 * ROWB + SWZ(r0, kb)));
    bf16x8 B1 = __builtin_bit_cast(bf16x8, *(const u32x4*)(sB + r1 * ROWB + SWZ(r1, kb)));
    xacc[0][0] = __builtin_amdgcn_mfma_f32_16x16x32_bf16(A0[kt], B0, xacc[0][0], 0, 0, 0);
    xacc[0][1] = __builtin_amdgcn_mfma_f32_16x16x32_bf16(A0[kt], B1, xacc[0][1], 0, 0, 0);
    xacc[1][0] = __builtin_amdgcn_mfma_f32_16x16x32_bf16(A1[kt], B0, xacc[1][0], 0, 0, 0);
    xacc[1][1] = __builtin_amdgcn_mfma_f32_16x16x32_bf16(A1[kt], B1, xacc[1][1], 0, 0, 0);
  }

  for (int t = 0; t < NT; ++t) {
    if (t > 0) {
      // self-timed: poll tagged h(t-1) words directly (2 batches of 16 u64)
      const u32 tagx = (u32)(t - 1);
      const u64* hsrc = hbuf + (((u64)(lstm * 2 + ((t & 1) ^ 1)) * 256 + b0) * 256);
      #pragma unroll
      for (int bi = 0; bi < 2; ++bi) {
        u64 hv[8][2];
        bool stale;
        do {
          #pragma unroll
          for (int i = 0; i < 8; ++i) {
            int lp = tid + (bi * 8 + i) * 256;
            int row = lp >> 7, c4 = lp & 127;
            const u64* p = hsrc + row * 256 + c4 * 2;
            hv[i][0] = __hip_atomic_load(&p[0], __ATOMIC_RELAXED, __HIP_MEMORY_SCOPE_AGENT);
            hv[i][1] = __hip_atomic_load(&p[1], __ATOMIC_RELAXED, __HIP_MEMORY_SCOPE_AGENT);
          }
          u32 acc = 0;
          #pragma unroll
          for (int i = 0; i < 8; ++i) {
            acc |= ((u32)hv[i][0] ^ tagx) & 0xFFFFu;
            acc |= ((u32)(hv[i][0] >> 32) ^ tagx) & 0xFFFFu;
            acc |= ((u32)hv[i][1] ^ tagx) & 0xFFFFu;
            acc |= ((u32)(hv[i][1] >> 32) ^ tagx) & 0xFFFFu;
          }
          stale = (acc != 0);
        } while (__any(stale));
        #pragma unroll
        for (int i = 0; i < 8; ++i) {
          int lp = tid + (bi * 8 + i) * 256;
          int row = lp >> 7, c4 = lp & 127;
          u32 lo = ((u32)(hv[i][0] >> 16) & 0xFFFFu) | ((u32)(hv[i][0] >> 32) & 0xFFFF0000u);
          u32 hi = ((u32)(hv[i][1] >> 16) & 0xFFFFu) | ((u32)(hv[i][1] >> 32) & 0xFFFF0000u);
          *(u64*)(sB + row * ROWB + SWZ(row, 640 + c4 * 8)) = (u64)lo | ((u64)hi << 32);
        }
      }
      LGKM0; BAR(); SCHED0;
      // h-GEMM: kt 10..25 (k in [320,832)), accumulate into xacc
      #pragma unroll
      for (int kt = 10; kt < 26; ++kt) {
        int kb = kt * 64 + ((l >> 4) << 4);
        bf16x8 B0 = __builtin_bit_cast(bf16x8, *(const u32x4*)(sB + r0 * ROWB + SWZ(r0, kb)));
        bf16x8 B1 = __builtin_bit_cast(bf16x8, *(const u32x4*)(sB + r1 * ROWB + SWZ(r1, kb)));
        xacc[0][0] = __builtin_amdgcn_mfma_f32_16x16x32_bf16(A0[kt], B0, xacc[0][0], 0, 0, 0);
        xacc[0][1] = __builtin_amdgcn_mfma_f32_16x16x32_bf16(A0[kt], B1, xacc[0][1], 0, 0, 0);
        xacc[1][0] = __builtin_amdgcn_mfma_f32_16x16x32_bf16(A1[kt], B0, xacc[1][0], 0, 0, 0);
        xacc[1][1] = __builtin_amdgcn_mfma_f32_16x16x32_bf16(A1[kt], B1, xacc[1][1], 0, 0, 0);
      }
    }

    // gates (acc reg r == gate r for cell (b,u): i,j,f,o)
    #pragma unroll
    for (int mf2 = 0; mf2 < 2; ++mf2)
      #pragma unroll
      for (int n = 0; n < 2; ++n) {
        f32x4 z = xacc[mf2][n];
        float zi = z[0] + bia[mf2][0];
        float zj = z[1] + bia[mf2][1];
        float zf = z[2] + bia[mf2][2];
        float zo = z[3] + bia[mf2][3];
        float cn = cst[mf2][n] * sigf(zf + 1.f) + sigf(zi) * tanhf_(zj);
        float hn = tanhf_(cn) * sigf(zo);
        if (t < lenn[n]) { cst[mf2][n] = cn; hst[mf2][n] = hn; }
        sH[n * 16 + (l & 15)][w * 8 + mf2 * 4 + (l >> 4)] = f2bf(hst[mf2][n]);
      }
    LGKM0; BAR(); SCHED0;

    // tagged h(t) store: fire-and-forget agent stores (no ack, no arrive)
    {
      int row = tid >> 3, q = tid & 7;
      u32 tg = (u32)t;
      u32 v0 = ((u32)sH[row][q * 4 + 0] << 16) | tg;
      u32 v1 = ((u32)sH[row][q * 4 + 1] << 16) | tg;
      u32 v2 = ((u32)sH[row][q * 4 + 2] << 16) | tg;
      u32 v3 = ((u32)sH[row][q * 4 + 3] << 16) | tg;
      u64* hdst = hbuf + (((u64)(lstm * 2 + (t & 1)) * 256 + b0 + row) * 256)
                       + (u0 >> 1) + q * 2;
      __hip_atomic_store(&hdst[0], (u64)v0 | ((u64)v1 << 32),
                         __ATOMIC_RELAXED, __HIP_MEMORY_SCOPE_AGENT);
      __hip_atomic_store(&hdst[1], (u64)v2 | ((u64)v3 << 32),
                         __ATOMIC_RELAXED, __HIP_MEMORY_SCOPE_AGENT);
    }
    // stage x(t+1) from px regs into LDS
    #pragma unroll
    for (int i = 0; i < 10; ++i)
      if (i < 9 || tid < 96) {
        float4 xv = px[i];
        u64 pk = (u64)f2bf(xv.x) | ((u64)f2bf(xv.y) << 16) |
                 ((u64)f2bf(xv.z) << 32) | ((u64)f2bf(xv.w) << 48);
        *(u64*)(sB + ldsoff[i]) = pk;
      }
    LGKM0; BAR(); SCHED0;   // x staged (no VM wait — stores self-validate)

    // prefetch x(t+2)
    {
      int tn2 = (t + 2) & (NT - 1);
      #pragma unroll
      for (int i = 0; i < 10; ++i)
        if (i < 9 || tid < 96) {
          int eid = sI[sirow[i] + tn2];
          px[i] = *(const float4*)(emb + eid * 300 + foff[i]);
        }
    }
    // x-GEMM(t+1): kt 0..9 into fresh xacc
    xacc[0][0] = {0.f,0.f,0.f,0.f}; xacc[0][1] = {0.f,0.f,0.f,0.f};
    xacc[1][0] = {0.f,0.f,0.f,0.f}; xacc[1][1] = {0.f,0.f,0.f,0.f};
    #pragma unroll
    for (int kt = 0; kt < 10; ++kt) {
      int kb = kt * 64 + ((l >> 4) << 4);
      bf16x8 B0 = __builtin_bit_cast(bf16x8, *(const u32x4*)(sB + r0 * ROWB + SWZ(r0, kb)));
      bf16x8 B1 = __builtin_bit_cast(bf16x8, *(const u32x4*)(sB + r1 * ROWB + SWZ(r1, kb)));
      xacc[0][0] = __builtin_amdgcn_mfma_f32_16x16x32_bf16(A0[kt], B0, xacc[0][0], 0, 0, 0);
      xacc[0][1] = __builtin_amdgcn_mfma_f32_16x16x32_bf16(A0[kt], B1, xacc[0][1], 0, 0, 0);
      xacc[1][0] = __builtin_amdgcn_mfma_f32_16x16x32_bf16(A1[kt], B0, xacc[1][0], 0, 0, 0);
      xacc[1][1] = __builtin_amdgcn_mfma_f32_16x16x32_bf16(A1[kt], B1, xacc[1][1], 0, 0, 0);
    }
  }

  // ---- dense partials: sOut[b][c] = sum_u h[b][u] * Wd[lstm*512+u][c] ----
  if (tid < 96) ((float*)sOut)[tid] = 0.f;
  __syncthreads();
  #pragma unroll
  for (int mf2 = 0; mf2 < 2; ++mf2)
    #pragma unroll
    for (int n = 0; n < 2; ++n) {
      int row = n * 16 + (l & 15);
      int uu = u0 + w * 8 + mf2 * 4 + (l >> 4);
      float h = hst[mf2][n];
      #pragma unroll
      for (int c = 0; c < 3; ++c)
        atomicAdd(&sOut[row][c], h * Wd[(lstm * 512 + uu) * 3 + c]);
    }
  __syncthreads();
  if (tid < 96) {
    int row = tid / 3, c = tid - (tid / 3) * 3;
    part[(lstm * 16 + ct) * 768 + (b0 + row) * 3 + c] = sOut[row][c];
  }
}

__global__ void dense_out(const float* __restrict__ part,
                          const float* __restrict__ bd, float* __restrict__ out) {
  const int b = blockIdx.x, l = threadIdx.x;
  if (l < 3) {
    float s = bd[l];
    #pragma unroll 4
    for (int k = 0; k < 32; ++k) s += part[k * 768 + b * 3 + l];
    out[b * 3 + l] = s;
  }
}

extern "C" void kernel_launch(void* const* d_in, const int* in_sizes, int n_in,
                              void* d_out, int out_size, void* d_ws, size_t ws_size,
                              hipStream_t stream) {
  const int*   lids = (const int*)d_in[0];
  const int*   rids = (const int*)d_in[1];
  const int*   llen = (const int*)d_in[2];
  const int*   rlen = (const int*)d_in[3];
  const float* emb  = (const float*)d_in[4];
  const float* Wl   = (const float*)d_in[5];
  const float* bl   = (const float*)d_in[6];
  const float* Wr   = (const float*)d_in[7];
  const float* br   = (const float*)d_in[8];
  const float* Wd   = (const float*)d_in[9];
  const float* bd   = (const float*)d_in[10];

  unsigned char* ws = (unsigned char*)d_ws;
  u64*   hbuf = (u64*)(ws + 4096);                   // 2 MiB tagged h
  float* part = (float*)(ws + 4096 + (2u << 20));    // 96 KiB dense partials

  hipMemsetAsync(hbuf, 0xFF, 2u << 20, stream);      // tag 0xFFFF != any step
  hipLaunchKernelGGL(lstm_persist, dim3(256), dim3(256), 0, stream,
                     lids, rids, llen, rlen, emb, Wl, bl, Wr, br, Wd, hbuf, part);
  hipLaunchKernelGGL(dense_out, dim3(256), dim3(64), 0, stream,
                     part, bd, (float*)d_out);
}

// Round 14
// 659.585 us; speedup vs baseline: 2.2455x; 1.1103x over previous
//
#include <hip/hip_runtime.h>

// TdLstm: twin BasicLSTM (i,j,f,o; forget_bias=1) + final dense.
// Round 14: r6 base (668us, best) with detection restructured:
//  - per-producer FLAG words (plain agent stores, no atomic RMW)
//  - ALL waves poll the 16-flag line concurrently (no tid0 bottleneck)
//  - post-detect s_barrier deleted (pre-arrive BAR still covers LDS hazards)
// Everything else identical to r6.
// ws: [0,2048) flags[16 grp][2 parity][16 ct] u32 (memset), [4096,+1MiB)
// h ping-pong (bf16), then 1MiB final h (f32).

using bf16x8 = __attribute__((ext_vector_type(8))) __bf16;
using f32x4  = __attribute__((ext_vector_type(4))) float;
using u32x4  = __attribute__((ext_vector_type(4))) unsigned int;
typedef unsigned short u16;
typedef unsigned int u32;
typedef unsigned long long u64;

#define NT 128
#define ROWB 1664                                  // 832 k-elems * 2B per B-row
#define SWZ(row, off) ((off) ^ (((row) & 7) << 4)) // bank swizzle, 16B granules

#define LGKM0  asm volatile("s_waitcnt lgkmcnt(0)" ::: "memory")
#define VM0    asm volatile("s_waitcnt vmcnt(0)" ::: "memory")
#define BAR()  __builtin_amdgcn_s_barrier()
#define SCHED0 __builtin_amdgcn_sched_barrier(0)

__device__ __forceinline__ u16 f2bf(float f) {
  union { float f; unsigned u; } v; v.f = f;
  unsigned r = v.u + 0x7fffu + ((v.u >> 16) & 1u);
  return (u16)(r >> 16);
}
__device__ __forceinline__ float sigf(float x) { return 1.f / (1.f + __expf(-x)); }
__device__ __forceinline__ float tanhf_(float x) { return 2.f / (1.f + __expf(-2.f * x)) - 1.f; }

// static-index store into A-fragment array (avoid scratch, rule #20)
__device__ __forceinline__ void setA26(bf16x8 (&A)[26], int kt, bf16x8 v) {
  switch (kt) {
    case 0:A[0]=v;break;  case 1:A[1]=v;break;  case 2:A[2]=v;break;
    case 3:A[3]=v;break;  case 4:A[4]=v;break;  case 5:A[5]=v;break;
    case 6:A[6]=v;break;  case 7:A[7]=v;break;  case 8:A[8]=v;break;
    case 9:A[9]=v;break;  case 10:A[10]=v;break; case 11:A[11]=v;break;
    case 12:A[12]=v;break; case 13:A[13]=v;break; case 14:A[14]=v;break;
    case 15:A[15]=v;break; case 16:A[16]=v;break; case 17:A[17]=v;break;
    case 18:A[18]=v;break; case 19:A[19]=v;break; case 20:A[20]=v;break;
    case 21:A[21]=v;break; case 22:A[22]=v;break; case 23:A[23]=v;break;
    case 24:A[24]=v;break; case 25:A[25]=v;break;
  }
}

__global__ __launch_bounds__(256, 1) void lstm_persist(
    const int* __restrict__ lids, const int* __restrict__ rids,
    const int* __restrict__ llen, const int* __restrict__ rlen,
    const float* __restrict__ emb,
    const float* __restrict__ Wl, const float* __restrict__ bl,
    const float* __restrict__ Wr, const float* __restrict__ br,
    u64* __restrict__ hbuf,      // [2 lstm][2 buf][256][128] u64 (bf16 x4)
    float* __restrict__ hfin,    // [2 lstm][256][512] f32
    u32* __restrict__ flags)     // [16 grp][2 parity][16 ct]
{
  __shared__ __align__(16) unsigned char sB[32 * ROWB]; // 52 KiB (also W scratch)
  __shared__ __align__(8)  u16 sH[32][36];              // h-out staging
  __shared__ int sI[4096];                              // ids[32 rows][128 t]

  const int tid = threadIdx.x;
  const int w = tid >> 6, l = tid & 63;
  const int bid = blockIdx.x;
  const int xcd = bid & 7, idx = bid >> 3;
  const int grp = xcd * 2 + (idx >> 4);   // 0..15 (lstm x b-tile)
  const int ct  = idx & 15;               // u-tile: u0 = ct*32
  const int lstm = grp >> 3, bt = grp & 7;
  const int b0 = bt * 32, u0 = ct * 32;

  const int*   ids  = lstm ? rids : lids;
  const int*   lenp = lstm ? rlen : llen;
  const float* W    = lstm ? Wr : Wl;
  const float* bv   = lstm ? br : bl;

  // ---- one-time: build W^T A-fragments (M-split: wave w owns mf=2w,2w+1) ----
  bf16x8 A0[26], A1[26];
  {
    float* sW = (float*)sB;                // [4 g][64 r][32 c] = 8192 floats
    for (int kc = 0; kc < 13; ++kc) {
      for (int i = 0; i < 32; ++i) {
        int id2 = tid + i * 256;
        int c = id2 & 31, r = (id2 >> 5) & 63, g = id2 >> 11;
        int kk = kc * 64 + r;
        float v = 0.f;
        if (kk < 300)       v = W[kk * 2048 + g * 512 + u0 + c];
        else if (kk >= 320) v = W[(kk - 20) * 2048 + g * 512 + u0 + c];
        sW[(g * 64 + r) * 32 + c] = v;
      }
      __syncthreads();
      #pragma unroll
      for (int kt2 = 0; kt2 < 2; ++kt2) {
        int kt = kc * 2 + kt2;
        #pragma unroll
        for (int mf2 = 0; mf2 < 2; ++mf2) {
          int mf = w * 2 + mf2;
          int rho = mf * 16 + (l & 15);    // col map rho = du*4 + g
          int du = rho >> 2, g = rho & 3;
          union { u16 s[8]; bf16x8 v; } tmp;
          #pragma unroll
          for (int j = 0; j < 8; ++j) {
            int kr = kt2 * 32 + ((l >> 4) << 3) + j;
            tmp.s[j] = f2bf(sW[(g * 64 + kr) * 32 + du]);
          }
          if (mf2 == 0) setA26(A0, kt, tmp.v); else setA26(A1, kt, tmp.v);
        }
      }
      __syncthreads();
    }
  }

  // zero-pad x region k in [300,320)
  if (tid < 160) {
    int row = tid / 5, c5 = tid - (tid / 5) * 5;
    *(u64*)(sB + row * ROWB + SWZ(row, 600 + c5 * 8)) = 0ULL;
  }
  // preload ids for this b-tile
  {
    const int* src = ids + b0 * NT;
    #pragma unroll
    for (int i = 0; i < 4; ++i)
      *(int4*)&sI[(tid + i * 256) * 4] = *(const int4*)&src[(tid + i * 256) * 4];
  }

  int ldsoff[10], sirow[10], foff[10];
  #pragma unroll
  for (int i = 0; i < 10; ++i) {
    int id2 = tid + i * 256;
    int row = (id2 < 2400) ? id2 / 75 : 0;
    int f4 = id2 - row * 75;
    ldsoff[i] = row * ROWB + SWZ(row, f4 * 8);
    sirow[i]  = row * NT;
    foff[i]   = f4 * 4;
  }
  int hoff[16];
  #pragma unroll
  for (int i = 0; i < 16; ++i) {
    int id2 = tid + i * 256;
    int row = id2 >> 7, c8 = id2 & 127;
    hoff[i] = row * ROWB + SWZ(row, 640 + c8 * 8);
  }

  int lenn[2];
  lenn[0] = lenp[b0 + (l & 15)];
  lenn[1] = lenp[b0 + 16 + (l & 15)];
  float bia[2][4];
  #pragma unroll
  for (int mf2 = 0; mf2 < 2; ++mf2) {
    int du = w * 8 + mf2 * 4 + (l >> 4);
    #pragma unroll
    for (int g = 0; g < 4; ++g) bia[mf2][g] = bv[g * 512 + u0 + du];
  }
  float cst[2][2] = {{0.f, 0.f}, {0.f, 0.f}};
  float hst[2][2] = {{0.f, 0.f}, {0.f, 0.f}};
  __syncthreads();

  // prologue: stage x(0), prefetch x(1)
  float4 px[10];
  #pragma unroll
  for (int i = 0; i < 10; ++i)
    if (i < 9 || tid < 96) {
      int eid = sI[sirow[i]];
      float4 xv = *(const float4*)(emb + eid * 300 + foff[i]);
      u64 pk = (u64)f2bf(xv.x) | ((u64)f2bf(xv.y) << 16) |
               ((u64)f2bf(xv.z) << 32) | ((u64)f2bf(xv.w) << 48);
      *(u64*)(sB + ldsoff[i]) = pk;
    }
  #pragma unroll
  for (int i = 0; i < 10; ++i)
    if (i < 9 || tid < 96) {
      int eid = sI[sirow[i] + 1];
      px[i] = *(const float4*)(emb + eid * 300 + foff[i]);
    }
  __syncthreads();

  const int r0 = l & 15, r1 = 16 + (l & 15);

  // x-GEMM(0): kt 0..9 (k < 320 region, x + zero pad)
  f32x4 xacc[2][2];
  xacc[0][0] = {0.f,0.f,0.f,0.f}; xacc[0][1] = {0.f,0.f,0.f,0.f};
  xacc[1][0] = {0.f,0.f,0.f,0.f}; xacc[1][1] = {0.f,0.f,0.f,0.f};
  #pragma unroll
  for (int kt = 0; kt < 10; ++kt) {
    int kb = kt * 64 + ((l >> 4) << 4);
    bf16x8 B0 = __builtin_bit_cast(bf16x8, *(const u32x4*)(sB + r0 * ROWB + SWZ(r0, kb)));
    bf16x8 B1 = __builtin_bit_cast(bf16x8, *(const u32x4*)(sB + r1 * ROWB + SWZ(r1, kb)));
    xacc[0][0] = __builtin_amdgcn_mfma_f32_16x16x32_bf16(A0[kt], B0, xacc[0][0], 0, 0, 0);
    xacc[0][1] = __builtin_amdgcn_mfma_f32_16x16x32_bf16(A0[kt], B1, xacc[0][1], 0, 0, 0);
    xacc[1][0] = __builtin_amdgcn_mfma_f32_16x16x32_bf16(A1[kt], B0, xacc[1][0], 0, 0, 0);
    xacc[1][1] = __builtin_amdgcn_mfma_f32_16x16x32_bf16(A1[kt], B1, xacc[1][1], 0, 0, 0);
  }

  for (int t = 0; t < NT; ++t) {
    if (t > 0) {
      // detect: ALL waves poll the 16-flag line (no RMW, no tid0, no BAR)
      {
        const u32* fl = flags + (grp * 2 + ((t & 1) ^ 1)) * 16;
        u32 fv; bool ok;
        do {
          fv = __hip_atomic_load(&fl[l & 15], __ATOMIC_RELAXED,
                                 __HIP_MEMORY_SCOPE_AGENT);
          ok = __all(fv >= (u32)t);
          if (!ok) __builtin_amdgcn_s_sleep(1);
        } while (!ok);
      }
      SCHED0;
      // h(t-1) loads (L3-coherent) -> LDS (per-wave, immediately after its poll)
      const u64* hsrc = hbuf + (((lstm * 2 + ((t & 1) ^ 1)) * 256) + b0) * 128;
      u64 hld[16];
      #pragma unroll
      for (int i = 0; i < 16; ++i)
        hld[i] = __hip_atomic_load(&hsrc[tid + i * 256], __ATOMIC_RELAXED,
                                   __HIP_MEMORY_SCOPE_AGENT);
      #pragma unroll
      for (int i = 0; i < 16; ++i) *(u64*)(sB + hoff[i]) = hld[i];
      LGKM0; BAR(); SCHED0;
      // h-GEMM: kt 10..25 (k in [320,832)), accumulate into xacc
      #pragma unroll
      for (int kt = 10; kt < 26; ++kt) {
        int kb = kt * 64 + ((l >> 4) << 4);
        bf16x8 B0 = __builtin_bit_cast(bf16x8, *(const u32x4*)(sB + r0 * ROWB + SWZ(r0, kb)));
        bf16x8 B1 = __builtin_bit_cast(bf16x8, *(const u32x4*)(sB + r1 * ROWB + SWZ(r1, kb)));
        xacc[0][0] = __builtin_amdgcn_mfma_f32_16x16x32_bf16(A0[kt], B0, xacc[0][0], 0, 0, 0);
        xacc[0][1] = __builtin_amdgcn_mfma_f32_16x16x32_bf16(A0[kt], B1, xacc[0][1], 0, 0, 0);
        xacc[1][0] = __builtin_amdgcn_mfma_f32_16x16x32_bf16(A1[kt], B0, xacc[1][0], 0, 0, 0);
        xacc[1][1] = __builtin_amdgcn_mfma_f32_16x16x32_bf16(A1[kt], B1, xacc[1][1], 0, 0, 0);
      }
    }

    // gates (acc reg r == gate r for cell (b,u): i,j,f,o)
    #pragma unroll
    for (int mf2 = 0; mf2 < 2; ++mf2)
      #pragma unroll
      for (int n = 0; n < 2; ++n) {
        f32x4 z = xacc[mf2][n];
        float zi = z[0] + bia[mf2][0];
        float zj = z[1] + bia[mf2][1];
        float zf = z[2] + bia[mf2][2];
        float zo = z[3] + bia[mf2][3];
        float cn = cst[mf2][n] * sigf(zf + 1.f) + sigf(zi) * tanhf_(zj);
        float hn = tanhf_(cn) * sigf(zo);
        if (t < lenn[n]) { cst[mf2][n] = cn; hst[mf2][n] = hn; }
        sH[n * 16 + (l & 15)][w * 8 + mf2 * 4 + (l >> 4)] = f2bf(hst[mf2][n]);
      }
    LGKM0; BAR(); SCHED0;

    // pack + coalesced u64 store of h(t) to L3
    {
      int bbL = tid >> 3, u8 = tid & 7;
      u64 pk = *(const u64*)&sH[bbL][u8 * 4];
      u64* hdst = hbuf + (((lstm * 2 + (t & 1)) * 256) + b0 + bbL) * 128 + (u0 >> 2) + u8;
      __hip_atomic_store(hdst, pk, __ATOMIC_RELAXED, __HIP_MEMORY_SCOPE_AGENT);
    }
    // stage x(t+1) from px regs into LDS (hides under store-ack)
    #pragma unroll
    for (int i = 0; i < 10; ++i)
      if (i < 9 || tid < 96) {
        float4 xv = px[i];
        u64 pk = (u64)f2bf(xv.x) | ((u64)f2bf(xv.y) << 16) |
                 ((u64)f2bf(xv.z) << 32) | ((u64)f2bf(xv.w) << 48);
        *(u64*)(sB + ldsoff[i]) = pk;
      }
    VM0; LGKM0; BAR();   // h stores acked at L3 + x staged, all waves

    // publish: plain agent store of my flag (no RMW)
    if (tid == 0)
      __hip_atomic_store(&flags[(grp * 2 + (t & 1)) * 16 + ct], (u32)(t + 1),
                         __ATOMIC_RELAXED, __HIP_MEMORY_SCOPE_AGENT);
    SCHED0;

    // prefetch x(t+2) (consumed next tail -> latency fully hidden)
    {
      int tn2 = (t + 2) & (NT - 1);
      #pragma unroll
      for (int i = 0; i < 10; ++i)
        if (i < 9 || tid < 96) {
          int eid = sI[sirow[i] + tn2];
          px[i] = *(const float4*)(emb + eid * 300 + foff[i]);
        }
    }
    // x-GEMM(t+1): kt 0..9 into fresh xacc (in the flag-skew shadow)
    xacc[0][0] = {0.f,0.f,0.f,0.f}; xacc[0][1] = {0.f,0.f,0.f,0.f};
    xacc[1][0] = {0.f,0.f,0.f,0.f}; xacc[1][1] = {0.f,0.f,0.f,0.f};
    #pragma unroll
    for (int kt = 0; kt < 10; ++kt) {
      int kb = kt * 64 + ((l >> 4) << 4);
      bf16x8 B0 = __builtin_bit_cast(bf16x8, *(const u32x4*)(sB + r0 * ROWB + SWZ(r0, kb)));
      bf16x8 B1 = __builtin_bit_cast(bf16x8, *(const u32x4*)(sB + r1 * ROWB + SWZ(r1, kb)));
      xacc[0][0] = __builtin_amdgcn_mfma_f32_16x16x32_bf16(A0[kt], B0, xacc[0][0], 0, 0, 0);
      xacc[0][1] = __builtin_amdgcn_mfma_f32_16x16x32_bf16(A0[kt], B1, xacc[0][1], 0, 0, 0);
      xacc[1][0] = __builtin_amdgcn_mfma_f32_16x16x32_bf16(A1[kt], B0, xacc[1][0], 0, 0, 0);
      xacc[1][1] = __builtin_amdgcn_mfma_f32_16x16x32_bf16(A1[kt], B1, xacc[1][1], 0, 0, 0);
    }
  }

  #pragma unroll
  for (int mf2 = 0; mf2 < 2; ++mf2)
    #pragma unroll
    for (int n = 0; n < 2; ++n) {
      int bb = b0 + n * 16 + (l & 15);
      int uu = u0 + w * 8 + mf2 * 4 + (l >> 4);
      hfin[lstm * (256 * 512) + bb * 512 + uu] = hst[mf2][n];
    }
}

__global__ void dense_out(const float* __restrict__ hfin,
                          const float* __restrict__ Wd, const float* __restrict__ bd,
                          float* __restrict__ out) {
  const int b = blockIdx.x, l = threadIdx.x;
  float a0 = 0.f, a1 = 0.f, a2 = 0.f;
  for (int i = l; i < 1024; i += 64) {
    float hv = (i < 512) ? hfin[b * 512 + i] : hfin[256 * 512 + b * 512 + (i - 512)];
    a0 += hv * Wd[i * 3 + 0];
    a1 += hv * Wd[i * 3 + 1];
    a2 += hv * Wd[i * 3 + 2];
  }
  #pragma unroll
  for (int off = 32; off > 0; off >>= 1) {
    a0 += __shfl_down(a0, off);
    a1 += __shfl_down(a1, off);
    a2 += __shfl_down(a2, off);
  }
  if (l == 0) {
    out[b * 3 + 0] = a0 + bd[0];
    out[b * 3 + 1] = a1 + bd[1];
    out[b * 3 + 2] = a2 + bd[2];
  }
}

extern "C" void kernel_launch(void* const* d_in, const int* in_sizes, int n_in,
                              void* d_out, int out_size, void* d_ws, size_t ws_size,
                              hipStream_t stream) {
  const int*   lids = (const int*)d_in[0];
  const int*   rids = (const int*)d_in[1];
  const int*   llen = (const int*)d_in[2];
  const int*   rlen = (const int*)d_in[3];
  const float* emb  = (const float*)d_in[4];
  const float* Wl   = (const float*)d_in[5];
  const float* bl   = (const float*)d_in[6];
  const float* Wr   = (const float*)d_in[7];
  const float* br   = (const float*)d_in[8];
  const float* Wd   = (const float*)d_in[9];
  const float* bd   = (const float*)d_in[10];

  unsigned char* ws = (unsigned char*)d_ws;
  u32*   flags = (u32*)ws;                           // 2 KiB flag area
  u64*   hbuf  = (u64*)(ws + 4096);                  // 1 MiB
  float* hfin  = (float*)(ws + 4096 + (1u << 20));   // 1 MiB

  hipMemsetAsync(flags, 0, 2048, stream);            // re-arm flags each call
  hipLaunchKernelGGL(lstm_persist, dim3(256), dim3(256), 0, stream,
                     lids, rids, llen, rlen, emb, Wl, bl, Wr, br, hbuf, hfin, flags);
  hipLaunchKernelGGL(dense_out, dim3(256), dim3(64), 0, stream,
                     hfin, Wd, bd, (float*)d_out);
}

// Round 15
// 652.583 us; speedup vs baseline: 2.2696x; 1.0107x over previous
//
#include <hip/hip_runtime.h>

// TdLstm: twin BasicLSTM (i,j,f,o; forget_bias=1) + final dense.
// Round 15: r14 base (660us) + phase-overlap trims:
//  - EARLY flag sample issued in the tail shadow; detect checks it first
//    (hit => poll RT eliminated from the serial chain)
//  - per-WAVE flag publish right after each wave's own VM0 (pre-barrier);
//    flags[grp][parity][ct][w], 64/group-parity -> poll = fl[l], all 64 lanes
//  - v_cvt_pk_bf16_f32 packing for x-stage (RNE, same numerics)
// Everything else identical to r14.
// ws: [0,8192) flags (memset), [8192,+1MiB) h ping-pong, then 1MiB final h.

using bf16x8 = __attribute__((ext_vector_type(8))) __bf16;
using f32x4  = __attribute__((ext_vector_type(4))) float;
using u32x4  = __attribute__((ext_vector_type(4))) unsigned int;
typedef unsigned short u16;
typedef unsigned int u32;
typedef unsigned long long u64;

#define NT 128
#define ROWB 1664                                  // 832 k-elems * 2B per B-row
#define SWZ(row, off) ((off) ^ (((row) & 7) << 4)) // bank swizzle, 16B granules

#define LGKM0  asm volatile("s_waitcnt lgkmcnt(0)" ::: "memory")
#define VM0    asm volatile("s_waitcnt vmcnt(0)" ::: "memory")
#define BAR()  __builtin_amdgcn_s_barrier()
#define SCHED0 __builtin_amdgcn_sched_barrier(0)

__device__ __forceinline__ u16 f2bf(float f) {
  union { float f; unsigned u; } v; v.f = f;
  unsigned r = v.u + 0x7fffu + ((v.u >> 16) & 1u);
  return (u16)(r >> 16);
}
__device__ __forceinline__ u32 cvtpk(float lo, float hi) {
  u32 r;
  asm("v_cvt_pk_bf16_f32 %0, %1, %2" : "=v"(r) : "v"(lo), "v"(hi));
  return r;
}
__device__ __forceinline__ u64 pack4(float4 xv) {
  return (u64)cvtpk(xv.x, xv.y) | ((u64)cvtpk(xv.z, xv.w) << 32);
}
__device__ __forceinline__ float sigf(float x) { return 1.f / (1.f + __expf(-x)); }
__device__ __forceinline__ float tanhf_(float x) { return 2.f / (1.f + __expf(-2.f * x)) - 1.f; }

// static-index store into A-fragment array (avoid scratch, rule #20)
__device__ __forceinline__ void setA26(bf16x8 (&A)[26], int kt, bf16x8 v) {
  switch (kt) {
    case 0:A[0]=v;break;  case 1:A[1]=v;break;  case 2:A[2]=v;break;
    case 3:A[3]=v;break;  case 4:A[4]=v;break;  case 5:A[5]=v;break;
    case 6:A[6]=v;break;  case 7:A[7]=v;break;  case 8:A[8]=v;break;
    case 9:A[9]=v;break;  case 10:A[10]=v;break; case 11:A[11]=v;break;
    case 12:A[12]=v;break; case 13:A[13]=v;break; case 14:A[14]=v;break;
    case 15:A[15]=v;break; case 16:A[16]=v;break; case 17:A[17]=v;break;
    case 18:A[18]=v;break; case 19:A[19]=v;break; case 20:A[20]=v;break;
    case 21:A[21]=v;break; case 22:A[22]=v;break; case 23:A[23]=v;break;
    case 24:A[24]=v;break; case 25:A[25]=v;break;
  }
}

__global__ __launch_bounds__(256, 1) void lstm_persist(
    const int* __restrict__ lids, const int* __restrict__ rids,
    const int* __restrict__ llen, const int* __restrict__ rlen,
    const float* __restrict__ emb,
    const float* __restrict__ Wl, const float* __restrict__ bl,
    const float* __restrict__ Wr, const float* __restrict__ br,
    u64* __restrict__ hbuf,      // [2 lstm][2 buf][256][128] u64 (bf16 x4)
    float* __restrict__ hfin,    // [2 lstm][256][512] f32
    u32* __restrict__ flags)     // [16 grp][2 parity][16 ct][4 w]
{
  __shared__ __align__(16) unsigned char sB[32 * ROWB]; // 52 KiB (also W scratch)
  __shared__ __align__(8)  u16 sH[32][36];              // h-out staging
  __shared__ int sI[4096];                              // ids[32 rows][128 t]

  const int tid = threadIdx.x;
  const int w = tid >> 6, l = tid & 63;
  const int bid = blockIdx.x;
  const int xcd = bid & 7, idx = bid >> 3;
  const int grp = xcd * 2 + (idx >> 4);   // 0..15 (lstm x b-tile)
  const int ct  = idx & 15;               // u-tile: u0 = ct*32
  const int lstm = grp >> 3, bt = grp & 7;
  const int b0 = bt * 32, u0 = ct * 32;

  const int*   ids  = lstm ? rids : lids;
  const int*   lenp = lstm ? rlen : llen;
  const float* W    = lstm ? Wr : Wl;
  const float* bv   = lstm ? br : bl;

  // ---- one-time: build W^T A-fragments (M-split: wave w owns mf=2w,2w+1) ----
  bf16x8 A0[26], A1[26];
  {
    float* sW = (float*)sB;                // [4 g][64 r][32 c] = 8192 floats
    for (int kc = 0; kc < 13; ++kc) {
      for (int i = 0; i < 32; ++i) {
        int id2 = tid + i * 256;
        int c = id2 & 31, r = (id2 >> 5) & 63, g = id2 >> 11;
        int kk = kc * 64 + r;
        float v = 0.f;
        if (kk < 300)       v = W[kk * 2048 + g * 512 + u0 + c];
        else if (kk >= 320) v = W[(kk - 20) * 2048 + g * 512 + u0 + c];
        sW[(g * 64 + r) * 32 + c] = v;
      }
      __syncthreads();
      #pragma unroll
      for (int kt2 = 0; kt2 < 2; ++kt2) {
        int kt = kc * 2 + kt2;
        #pragma unroll
        for (int mf2 = 0; mf2 < 2; ++mf2) {
          int mf = w * 2 + mf2;
          int rho = mf * 16 + (l & 15);    // col map rho = du*4 + g
          int du = rho >> 2, g = rho & 3;
          union { u16 s[8]; bf16x8 v; } tmp;
          #pragma unroll
          for (int j = 0; j < 8; ++j) {
            int kr = kt2 * 32 + ((l >> 4) << 3) + j;
            tmp.s[j] = f2bf(sW[(g * 64 + kr) * 32 + du]);
          }
          if (mf2 == 0) setA26(A0, kt, tmp.v); else setA26(A1, kt, tmp.v);
        }
      }
      __syncthreads();
    }
  }

  // zero-pad x region k in [300,320)
  if (tid < 160) {
    int row = tid / 5, c5 = tid - (tid / 5) * 5;
    *(u64*)(sB + row * ROWB + SWZ(row, 600 + c5 * 8)) = 0ULL;
  }
  // preload ids for this b-tile
  {
    const int* src = ids + b0 * NT;
    #pragma unroll
    for (int i = 0; i < 4; ++i)
      *(int4*)&sI[(tid + i * 256) * 4] = *(const int4*)&src[(tid + i * 256) * 4];
  }

  int ldsoff[10], sirow[10], foff[10];
  #pragma unroll
  for (int i = 0; i < 10; ++i) {
    int id2 = tid + i * 256;
    int row = (id2 < 2400) ? id2 / 75 : 0;
    int f4 = id2 - row * 75;
    ldsoff[i] = row * ROWB + SWZ(row, f4 * 8);
    sirow[i]  = row * NT;
    foff[i]   = f4 * 4;
  }
  int hoff[16];
  #pragma unroll
  for (int i = 0; i < 16; ++i) {
    int id2 = tid + i * 256;
    int row = id2 >> 7, c8 = id2 & 127;
    hoff[i] = row * ROWB + SWZ(row, 640 + c8 * 8);
  }

  int lenn[2];
  lenn[0] = lenp[b0 + (l & 15)];
  lenn[1] = lenp[b0 + 16 + (l & 15)];
  float bia[2][4];
  #pragma unroll
  for (int mf2 = 0; mf2 < 2; ++mf2) {
    int du = w * 8 + mf2 * 4 + (l >> 4);
    #pragma unroll
    for (int g = 0; g < 4; ++g) bia[mf2][g] = bv[g * 512 + u0 + du];
  }
  float cst[2][2] = {{0.f, 0.f}, {0.f, 0.f}};
  float hst[2][2] = {{0.f, 0.f}, {0.f, 0.f}};
  __syncthreads();

  // prologue: stage x(0), prefetch x(1)
  float4 px[10];
  #pragma unroll
  for (int i = 0; i < 10; ++i)
    if (i < 9 || tid < 96) {
      int eid = sI[sirow[i]];
      float4 xv = *(const float4*)(emb + eid * 300 + foff[i]);
      *(u64*)(sB + ldsoff[i]) = pack4(xv);
    }
  #pragma unroll
  for (int i = 0; i < 10; ++i)
    if (i < 9 || tid < 96) {
      int eid = sI[sirow[i] + 1];
      px[i] = *(const float4*)(emb + eid * 300 + foff[i]);
    }
  __syncthreads();

  const int r0 = l & 15, r1 = 16 + (l & 15);

  // x-GEMM(0): kt 0..9 (k < 320 region, x + zero pad)
  f32x4 xacc[2][2];
  xacc[0][0] = {0.f,0.f,0.f,0.f}; xacc[0][1] = {0.f,0.f,0.f,0.f};
  xacc[1][0] = {0.f,0.f,0.f,0.f}; xacc[1][1] = {0.f,0.f,0.f,0.f};
  #pragma unroll
  for (int kt = 0; kt < 10; ++kt) {
    int kb = kt * 64 + ((l >> 4) << 4);
    bf16x8 B0 = __builtin_bit_cast(bf16x8, *(const u32x4*)(sB + r0 * ROWB + SWZ(r0, kb)));
    bf16x8 B1 = __builtin_bit_cast(bf16x8, *(const u32x4*)(sB + r1 * ROWB + SWZ(r1, kb)));
    xacc[0][0] = __builtin_amdgcn_mfma_f32_16x16x32_bf16(A0[kt], B0, xacc[0][0], 0, 0, 0);
    xacc[0][1] = __builtin_amdgcn_mfma_f32_16x16x32_bf16(A0[kt], B1, xacc[0][1], 0, 0, 0);
    xacc[1][0] = __builtin_amdgcn_mfma_f32_16x16x32_bf16(A1[kt], B0, xacc[1][0], 0, 0, 0);
    xacc[1][1] = __builtin_amdgcn_mfma_f32_16x16x32_bf16(A1[kt], B1, xacc[1][1], 0, 0, 0);
  }

  u32 fa = 0;   // early-sampled flag word (lane l -> flag[ct=l>>2... = index l])

  for (int t = 0; t < NT; ++t) {
    if (t > 0) {
      // detect: check tail-shadow sample first; on miss, poll (all 64 lanes)
      {
        const u32* fl = flags + (grp * 2 + ((t & 1) ^ 1)) * 64;
        bool ok = __all(fa >= (u32)t);
        while (!ok) {
          fa = __hip_atomic_load(&fl[l], __ATOMIC_RELAXED, __HIP_MEMORY_SCOPE_AGENT);
          ok = __all(fa >= (u32)t);
          if (!ok) __builtin_amdgcn_s_sleep(1);
        }
      }
      SCHED0;
      // h(t-1) loads (L3-coherent) -> LDS
      const u64* hsrc = hbuf + (((lstm * 2 + ((t & 1) ^ 1)) * 256) + b0) * 128;
      u64 hld[16];
      #pragma unroll
      for (int i = 0; i < 16; ++i)
        hld[i] = __hip_atomic_load(&hsrc[tid + i * 256], __ATOMIC_RELAXED,
                                   __HIP_MEMORY_SCOPE_AGENT);
      #pragma unroll
      for (int i = 0; i < 16; ++i) *(u64*)(sB + hoff[i]) = hld[i];
      LGKM0; BAR(); SCHED0;
      // h-GEMM: kt 10..25 (k in [320,832)), accumulate into xacc
      #pragma unroll
      for (int kt = 10; kt < 26; ++kt) {
        int kb = kt * 64 + ((l >> 4) << 4);
        bf16x8 B0 = __builtin_bit_cast(bf16x8, *(const u32x4*)(sB + r0 * ROWB + SWZ(r0, kb)));
        bf16x8 B1 = __builtin_bit_cast(bf16x8, *(const u32x4*)(sB + r1 * ROWB + SWZ(r1, kb)));
        xacc[0][0] = __builtin_amdgcn_mfma_f32_16x16x32_bf16(A0[kt], B0, xacc[0][0], 0, 0, 0);
        xacc[0][1] = __builtin_amdgcn_mfma_f32_16x16x32_bf16(A0[kt], B1, xacc[0][1], 0, 0, 0);
        xacc[1][0] = __builtin_amdgcn_mfma_f32_16x16x32_bf16(A1[kt], B0, xacc[1][0], 0, 0, 0);
        xacc[1][1] = __builtin_amdgcn_mfma_f32_16x16x32_bf16(A1[kt], B1, xacc[1][1], 0, 0, 0);
      }
    }

    // gates (acc reg r == gate r for cell (b,u): i,j,f,o)
    #pragma unroll
    for (int mf2 = 0; mf2 < 2; ++mf2)
      #pragma unroll
      for (int n = 0; n < 2; ++n) {
        f32x4 z = xacc[mf2][n];
        float zi = z[0] + bia[mf2][0];
        float zj = z[1] + bia[mf2][1];
        float zf = z[2] + bia[mf2][2];
        float zo = z[3] + bia[mf2][3];
        float cn = cst[mf2][n] * sigf(zf + 1.f) + sigf(zi) * tanhf_(zj);
        float hn = tanhf_(cn) * sigf(zo);
        if (t < lenn[n]) { cst[mf2][n] = cn; hst[mf2][n] = hn; }
        sH[n * 16 + (l & 15)][w * 8 + mf2 * 4 + (l >> 4)] = f2bf(hst[mf2][n]);
      }
    LGKM0; BAR(); SCHED0;

    // pack + coalesced u64 store of h(t) to L3
    {
      int bbL = tid >> 3, u8 = tid & 7;
      u64 pk = *(const u64*)&sH[bbL][u8 * 4];
      u64* hdst = hbuf + (((lstm * 2 + (t & 1)) * 256) + b0 + bbL) * 128 + (u0 >> 2) + u8;
      __hip_atomic_store(hdst, pk, __ATOMIC_RELAXED, __HIP_MEMORY_SCOPE_AGENT);
    }
    // stage x(t+1) from px regs into LDS (hides under store-ack)
    #pragma unroll
    for (int i = 0; i < 10; ++i)
      if (i < 9 || tid < 96)
        *(u64*)(sB + ldsoff[i]) = pack4(px[i]);
    VM0;   // this wave's h-store acked at L3

    // per-WAVE publish (before barrier: no wait on other waves)
    if (l == 0)
      __hip_atomic_store(&flags[(grp * 2 + (t & 1)) * 64 + ct * 4 + w], (u32)(t + 1),
                         __ATOMIC_RELAXED, __HIP_MEMORY_SCOPE_AGENT);
    LGKM0; BAR(); SCHED0;   // x staged by all threads before x-GEMM

    // prefetch x(t+2) (consumed next tail -> latency fully hidden)
    {
      int tn2 = (t + 2) & (NT - 1);
      #pragma unroll
      for (int i = 0; i < 10; ++i)
        if (i < 9 || tid < 96) {
          int eid = sI[sirow[i] + tn2];
          px[i] = *(const float4*)(emb + eid * 300 + foff[i]);
        }
    }
    // x-GEMM(t+1): kt 0..9 into fresh xacc (in the flag-skew shadow)
    xacc[0][0] = {0.f,0.f,0.f,0.f}; xacc[0][1] = {0.f,0.f,0.f,0.f};
    xacc[1][0] = {0.f,0.f,0.f,0.f}; xacc[1][1] = {0.f,0.f,0.f,0.f};
    #pragma unroll
    for (int kt = 0; kt < 10; ++kt) {
      int kb = kt * 64 + ((l >> 4) << 4);
      bf16x8 B0 = __builtin_bit_cast(bf16x8, *(const u32x4*)(sB + r0 * ROWB + SWZ(r0, kb)));
      bf16x8 B1 = __builtin_bit_cast(bf16x8, *(const u32x4*)(sB + r1 * ROWB + SWZ(r1, kb)));
      xacc[0][0] = __builtin_amdgcn_mfma_f32_16x16x32_bf16(A0[kt], B0, xacc[0][0], 0, 0, 0);
      xacc[0][1] = __builtin_amdgcn_mfma_f32_16x16x32_bf16(A0[kt], B1, xacc[0][1], 0, 0, 0);
      xacc[1][0] = __builtin_amdgcn_mfma_f32_16x16x32_bf16(A1[kt], B0, xacc[1][0], 0, 0, 0);
      xacc[1][1] = __builtin_amdgcn_mfma_f32_16x16x32_bf16(A1[kt], B1, xacc[1][1], 0, 0, 0);
    }

    // EARLY sample for next step's detect (tail shadow; stale -> poll loop)
    fa = __hip_atomic_load(&flags[(grp * 2 + (t & 1)) * 64 + l],
                           __ATOMIC_RELAXED, __HIP_MEMORY_SCOPE_AGENT);
  }

  #pragma unroll
  for (int mf2 = 0; mf2 < 2; ++mf2)
    #pragma unroll
    for (int n = 0; n < 2; ++n) {
      int bb = b0 + n * 16 + (l & 15);
      int uu = u0 + w * 8 + mf2 * 4 + (l >> 4);
      hfin[lstm * (256 * 512) + bb * 512 + uu] = hst[mf2][n];
    }
}

__global__ void dense_out(const float* __restrict__ hfin,
                          const float* __restrict__ Wd, const float* __restrict__ bd,
                          float* __restrict__ out) {
  const int b = blockIdx.x, l = threadIdx.x;
  float a0 = 0.f, a1 = 0.f, a2 = 0.f;
  for (int i = l; i < 1024; i += 64) {
    float hv = (i < 512) ? hfin[b * 512 + i] : hfin[256 * 512 + b * 512 + (i - 512)];
    a0 += hv * Wd[i * 3 + 0];
    a1 += hv * Wd[i * 3 + 1];
    a2 += hv * Wd[i * 3 + 2];
  }
  #pragma unroll
  for (int off = 32; off > 0; off >>= 1) {
    a0 += __shfl_down(a0, off);
    a1 += __shfl_down(a1, off);
    a2 += __shfl_down(a2, off);
  }
  if (l == 0) {
    out[b * 3 + 0] = a0 + bd[0];
    out[b * 3 + 1] = a1 + bd[1];
    out[b * 3 + 2] = a2 + bd[2];
  }
}

extern "C" void kernel_launch(void* const* d_in, const int* in_sizes, int n_in,
                              void* d_out, int out_size, void* d_ws, size_t ws_size,
                              hipStream_t stream) {
  const int*   lids = (const int*)d_in[0];
  const int*   rids = (const int*)d_in[1];
  const int*   llen = (const int*)d_in[2];
  const int*   rlen = (const int*)d_in[3];
  const float* emb  = (const float*)d_in[4];
  const float* Wl   = (const float*)d_in[5];
  const float* bl   = (const float*)d_in[6];
  const float* Wr   = (const float*)d_in[7];
  const float* br   = (const float*)d_in[8];
  const float* Wd   = (const float*)d_in[9];
  const float* bd   = (const float*)d_in[10];

  unsigned char* ws = (unsigned char*)d_ws;
  u32*   flags = (u32*)ws;                           // 8 KiB flag area
  u64*   hbuf  = (u64*)(ws + 8192);                  // 1 MiB
  float* hfin  = (float*)(ws + 8192 + (1u << 20));   // 1 MiB

  hipMemsetAsync(flags, 0, 8192, stream);            // re-arm flags each call
  hipLaunchKernelGGL(lstm_persist, dim3(256), dim3(256), 0, stream,
                     lids, rids, llen, rlen, emb, Wl, bl, Wr, br, hbuf, hfin, flags);
  hipLaunchKernelGGL(dense_out, dim3(256), dim3(64), 0, stream,
                     hfin, Wd, bd, (float*)d_out);
}